// Round 7
// baseline (765.296 us; speedup 1.0000x reference)
//
#include <hip/hip_runtime.h>
#include <math.h>

#define BB 16
#define LL 4096
#define HH 128
#define NN2 32
#define NLAYERS 4
#define DOUTN 100
#define TWOH 256
#define ST 64      // steps per chunk (scan)
#define NCH 64     // chunks per row

typedef __attribute__((ext_vector_type(8))) short short8;
typedef __attribute__((ext_vector_type(4))) float f32x4;

__device__ __forceinline__ unsigned short f2bf(float f) {
    unsigned int u = __builtin_bit_cast(unsigned int, f);
    unsigned int r = (u + 0x7FFFu + ((u >> 16) & 1u)) >> 16;
    return (unsigned short)r;
}
__device__ __forceinline__ float bf2f(unsigned short s) {
    unsigned int u = ((unsigned int)s) << 16;
    return __builtin_bit_cast(float, u);
}
__device__ __forceinline__ unsigned packbf(float v) {
    unsigned short hh = f2bf(v);
    unsigned short ll = f2bf(v - bf2f(hh));
    return ((unsigned)hh << 16) | (unsigned)ll;
}

// ---------------- pack out_w (nl,2H,H) into MFMA A-fragment layout, bf16 hi/lo ----------------
__global__ __launch_bounds__(256) void k_pack(const float* __restrict__ out_w,
                                              short* __restrict__ Ahi, short* __restrict__ Alo) {
    int idx = blockIdx.x * 256 + threadIdx.x;          // 4*16*4*64 = 16384
    if (idx >= NLAYERS * 16 * 4 * 64) return;
    int lane = idx & 63;
    int ks   = (idx >> 6) & 3;
    int ot   = (idx >> 8) & 15;
    int layer = idx >> 12;
    int o = ot * 16 + (lane & 15);
    short8 hi, lo;
#pragma unroll
    for (int e = 0; e < 8; ++e) {
        int h = ks * 32 + (lane >> 4) * 8 + e;
        float w = out_w[((size_t)(layer * TWOH + o)) * HH + h];
        unsigned short wh = f2bf(w);
        hi[e] = (short)wh;
        lo[e] = (short)f2bf(w - bf2f(wh));
    }
    *(short8*)(Ahi + (size_t)idx * 8) = hi;
    *(short8*)(Alo + (size_t)idx * 8) = lo;
}

// ---------------- build per-(layer,h) scan matrices as MFMA A-frags ----------------
// M_big rows 0..63 = T (Toeplitz k[j-i]), rows 64..127 = F (state collector).
// E separate (boundary->output). Frag order f: 0..15 = [T;F] (mt*2+kt), 16..23 = E.
__global__ __launch_bounds__(64) void k_mats(const float* __restrict__ log_dt, const float* __restrict__ Cc,
                                             const float* __restrict__ log_A_real, const float* __restrict__ A_imag,
                                             int layer, short* __restrict__ SAhi, short* __restrict__ SAlo) {
    __shared__ float kker[64];
    __shared__ float Mb[128][66];
    __shared__ float El[64][66];
    int h = blockIdx.x;
    int lane = threadIdx.x;
    float dt = expf(log_dt[layer * HH + h]);
    float kacc = 0.0f;
    float fl = (float)lane;
    float f2_ = (float)(63 - lane);
#pragma unroll 1
    for (int n = 0; n < NN2; ++n) {
        int pidx = (layer * HH + h) * NN2 + n;
        float Ar  = -expf(log_A_real[pidx]);
        float Ai  = A_imag[pidx];
        float dAr = Ar * dt, dAi = Ai * dt;
        float el  = expf(dAr);
        float lr  = el * cosf(dAi), li = el * sinf(dAi);
        float nr  = lr - 1.0f, ni = li;
        float inv = 1.0f / (Ar * Ar + Ai * Ai);
        float gr  = (nr * Ar + ni * Ai) * inv;
        float gi  = (ni * Ar - nr * Ai) * inv;
        float Cre = Cc[pidx * 2], Cim = Cc[pidx * 2 + 1];
        float c2r = 2.0f * (Cre * gr - Cim * gi);
        float c2i = 2.0f * (Cre * gi + Cim * gr);
        // p1 = lam^lane
        float e1 = expf(dAr * fl), a1 = dAi * fl;
        float p1r = e1 * cosf(a1), p1i = e1 * sinf(a1);
        kacc += c2r * p1r - c2i * p1i;
        // p2 = lam^(63-lane)  (F column entries)
        float e2 = expf(dAr * f2_), a2 = dAi * f2_;
        Mb[64 + 2 * n][lane]     = e2 * cosf(a2);
        Mb[64 + 2 * n + 1][lane] = e2 * sinf(a2);
        // p3 = lam^(lane+1) = lam * p1  (E row entries)
        float p3r = lr * p1r - li * p1i;
        float p3i = lr * p1i + li * p1r;
        El[lane][2 * n]     =  c2r * p3r - c2i * p3i;
        El[lane][2 * n + 1] = -(c2r * p3i + c2i * p3r);
    }
    kker[lane] = kacc;
    __syncthreads();
    for (int j = 0; j < 64; ++j)
        Mb[j][lane] = (j >= lane) ? kker[j - lane] : 0.0f;
    __syncthreads();
    int r = lane & 15, kgq = lane >> 4;
    short* baseH = SAhi + (size_t)h * 24 * 64 * 8;
    short* baseL = SAlo + (size_t)h * 24 * 64 * 8;
#pragma unroll 1
    for (int f = 0; f < 24; ++f) {
        int loc = (f < 16) ? f : (f - 16);
        int mt = loc >> 1, kt = loc & 1;
        int rowb = mt * 16 + r;
        int kcol = kt * 32 + kgq * 8;
        short8 hi8, lo8;
#pragma unroll
        for (int e = 0; e < 8; ++e) {
            float v = (f < 16) ? Mb[rowb][kcol + e] : El[rowb][kcol + e];
            unsigned short hh = f2bf(v);
            hi8[e] = (short)hh;
            lo8[e] = (short)f2bf(v - bf2f(hh));
        }
        *(short8*)(baseH + ((size_t)f * 64 + lane) * 8) = hi8;
        *(short8*)(baseL + ((size_t)f * 64 + lane) * 8) = lo8;
    }
}

// ---------------- encoder ----------------
__global__ __launch_bounds__(256) void k_enc(const float* __restrict__ x, const float* __restrict__ enc_w,
                                             const float* __restrict__ enc_b, float* __restrict__ hbuf) {
    int idx = blockIdx.x * 256 + threadIdx.x;
    int l4 = idx & (LL / 4 - 1);
    int h  = (idx / (LL / 4)) & (HH - 1);
    int b  = idx / (LL / 4 * HH);
    float4 xv = ((const float4*)(x + (size_t)b * LL))[l4];
    float w = enc_w[h], bb = enc_b[h];
    float4 o;
    o.x = fmaf(xv.x, w, bb);
    o.y = fmaf(xv.y, w, bb);
    o.z = fmaf(xv.z, w, bb);
    o.w = fmaf(xv.w, w, bb);
    ((float4*)(hbuf + ((size_t)b * HH + h) * LL))[l4] = o;
}

// ---------------- SSM scan via MFMA: Y = T*U + E*S_in, S_fin = F*U, wave0 prefix ----------------
__global__ __launch_bounds__(256, 2) void k_scan(const float* __restrict__ u_, float* __restrict__ y_,
                                                 const float* __restrict__ log_dt,
                                                 const float* __restrict__ log_A_real,
                                                 const float* __restrict__ A_imag,
                                                 const short* __restrict__ SAhi, const short* __restrict__ SAlo,
                                                 int layer) {
    __shared__ unsigned Ul[64][68];   // packed bf16 hi|lo of u, [chunk][step]; reused as Y fp32
    __shared__ float Sf[64][68];      // S_fin [comp][chunk]
    __shared__ float Si[64][68];      // S_in  [chunk][comp]
    int row = blockIdx.x;             // b*H + h
    int h = row & (HH - 1);
    int tid = threadIdx.x;
    const float* urow = u_ + (size_t)row * LL;
    float* yrow = y_ + (size_t)row * LL;
    int wave = tid >> 6, lane = tid & 63;
    int n15 = lane & 15, kg = lane >> 4;

    // A-frag loads (independent of LDS)
    const short* bH = SAhi + (size_t)h * 24 * 64 * 8;
    const short* bL = SAlo + (size_t)h * 24 * 64 * 8;
    short8 A1h0[2], A1l0[2], A1h1[2], A1l1[2], A2h[2], A2l[2];
#pragma unroll
    for (int kt = 0; kt < 2; ++kt) {
        int f0 = wave * 2 + kt;          // T rows (mt = wave)
        int f1 = (wave + 4) * 2 + kt;    // F rows (mt = wave+4)
        int fe = 16 + wave * 2 + kt;     // E rows (mt = wave)
        A1h0[kt] = *(const short8*)(bH + ((size_t)f0 * 64 + lane) * 8);
        A1l0[kt] = *(const short8*)(bL + ((size_t)f0 * 64 + lane) * 8);
        A1h1[kt] = *(const short8*)(bH + ((size_t)f1 * 64 + lane) * 8);
        A1l1[kt] = *(const short8*)(bL + ((size_t)f1 * 64 + lane) * 8);
        A2h[kt]  = *(const short8*)(bH + ((size_t)fe * 64 + lane) * 8);
        A2l[kt]  = *(const short8*)(bL + ((size_t)fe * 64 + lane) * 8);
    }

    // stage u -> LDS packed bf16 hi/lo
    {
        int c  = tid >> 2;
        int i0 = (tid & 3) << 4;
        const float* up = urow + ((size_t)tid << 4);
        float vv[16];
        *(float4*)&vv[0]  = *(const float4*)(up);
        *(float4*)&vv[4]  = *(const float4*)(up + 4);
        *(float4*)&vv[8]  = *(const float4*)(up + 8);
        *(float4*)&vv[12] = *(const float4*)(up + 12);
#pragma unroll
        for (int q = 0; q < 4; ++q) {
            uint4 w;
            w.x = packbf(vv[q * 4 + 0]);
            w.y = packbf(vv[q * 4 + 1]);
            w.z = packbf(vv[q * 4 + 2]);
            w.w = packbf(vv[q * 4 + 3]);
            *(uint4*)&Ul[c][i0 + q * 4] = w;
        }
    }
    __syncthreads();

    // U B-frags: B[k=i][n=c]
    short8 Bh[4][2], Bl[4][2];
#pragma unroll
    for (int nt = 0; nt < 4; ++nt) {
        int c = nt * 16 + n15;
#pragma unroll
        for (int kt = 0; kt < 2; ++kt) {
            int i0 = kt * 32 + kg * 8;
            uint4 w0 = *(const uint4*)&Ul[c][i0];
            uint4 w1 = *(const uint4*)&Ul[c][i0 + 4];
            unsigned wv[8] = {w0.x, w0.y, w0.z, w0.w, w1.x, w1.y, w1.z, w1.w};
#pragma unroll
            for (int e = 0; e < 8; ++e) {
                Bh[nt][kt][e] = (short)(wv[e] >> 16);
                Bl[nt][kt][e] = (short)(wv[e] & 0xFFFFu);
            }
        }
    }

    // GEMM1: [T;F] x U  (3-pass hi/lo)
    f32x4 accT[4], accF[4];
#pragma unroll
    for (int nt = 0; nt < 4; ++nt) { accT[nt] = (f32x4)(0.0f); accF[nt] = (f32x4)(0.0f); }
#pragma unroll
    for (int nt = 0; nt < 4; ++nt) {
#pragma unroll
        for (int kt = 0; kt < 2; ++kt) {
            accT[nt] = __builtin_amdgcn_mfma_f32_16x16x32_bf16(A1h0[kt], Bh[nt][kt], accT[nt], 0, 0, 0);
            accT[nt] = __builtin_amdgcn_mfma_f32_16x16x32_bf16(A1h0[kt], Bl[nt][kt], accT[nt], 0, 0, 0);
            accT[nt] = __builtin_amdgcn_mfma_f32_16x16x32_bf16(A1l0[kt], Bh[nt][kt], accT[nt], 0, 0, 0);
            accF[nt] = __builtin_amdgcn_mfma_f32_16x16x32_bf16(A1h1[kt], Bh[nt][kt], accF[nt], 0, 0, 0);
            accF[nt] = __builtin_amdgcn_mfma_f32_16x16x32_bf16(A1h1[kt], Bl[nt][kt], accF[nt], 0, 0, 0);
            accF[nt] = __builtin_amdgcn_mfma_f32_16x16x32_bf16(A1l1[kt], Bh[nt][kt], accF[nt], 0, 0, 0);
        }
    }

    // dump S_fin: comp = wave*16 + kg*4 + e, c = nt*16 + n15
#pragma unroll
    for (int nt = 0; nt < 4; ++nt)
#pragma unroll
        for (int e = 0; e < 4; ++e)
            Sf[wave * 16 + kg * 4 + e][nt * 16 + n15] = accF[nt][e];
    __syncthreads();

    // wave0: complex prefix over 64 chunks with M = lam^64, then shift -> S_in
    if (wave == 0) {
        float dtv = expf(log_dt[layer * HH + h]);
        float mrr[NN2], mii[NN2], srr[NN2], sii[NN2];
#pragma unroll
        for (int n = 0; n < NN2; ++n) {
            int pidx = (layer * HH + h) * NN2 + n;
            float Ar = -expf(log_A_real[pidx]);
            float Ai = A_imag[pidx];
            float dAr = Ar * dtv, dAi = Ai * dtv;
            float e64 = expf(dAr * 64.0f), a64 = dAi * 64.0f;
            mrr[n] = e64 * cosf(a64);
            mii[n] = e64 * sinf(a64);
        }
#pragma unroll
        for (int n = 0; n < NN2; ++n) { srr[n] = Sf[2 * n][lane]; sii[n] = Sf[2 * n + 1][lane]; }
#pragma unroll
        for (int k = 1; k < 64; k <<= 1) {
#pragma unroll
            for (int n = 0; n < NN2; ++n) {
                float vr = __shfl_up(srr[n], k);
                float vi = __shfl_up(sii[n], k);
                vr = (lane >= k) ? vr : 0.0f;
                vi = (lane >= k) ? vi : 0.0f;
                srr[n] = fmaf(mrr[n], vr, fmaf(-mii[n], vi, srr[n]));
                sii[n] = fmaf(mrr[n], vi, fmaf(mii[n], vr, sii[n]));
            }
#pragma unroll
            for (int n = 0; n < NN2; ++n) {
                float t = fmaf(mrr[n], mrr[n], -(mii[n] * mii[n]));
                mii[n] = 2.0f * mrr[n] * mii[n];
                mrr[n] = t;
            }
        }
#pragma unroll
        for (int n = 0; n < NN2; ++n) {
            float vr = __shfl_up(srr[n], 1);
            float vi = __shfl_up(sii[n], 1);
            Si[lane][2 * n]     = (lane >= 1) ? vr : 0.0f;
            Si[lane][2 * n + 1] = (lane >= 1) ? vi : 0.0f;
        }
    }
    __syncthreads();

    // S_in B-frags: B[k=comp][n=c]
    short8 Ch[4][2], Cl[4][2];
#pragma unroll
    for (int nt = 0; nt < 4; ++nt) {
        int c = nt * 16 + n15;
#pragma unroll
        for (int kt = 0; kt < 2; ++kt) {
            int k0 = kt * 32 + kg * 8;
            float fv[8];
            *(float4*)&fv[0] = *(const float4*)&Si[c][k0];
            *(float4*)&fv[4] = *(const float4*)&Si[c][k0 + 4];
#pragma unroll
            for (int e = 0; e < 8; ++e) {
                unsigned short hh = f2bf(fv[e]);
                Ch[nt][kt][e] = (short)hh;
                Cl[nt][kt][e] = (short)f2bf(fv[e] - bf2f(hh));
            }
        }
    }

    // GEMM2: += E x S_in
#pragma unroll
    for (int nt = 0; nt < 4; ++nt) {
#pragma unroll
        for (int kt = 0; kt < 2; ++kt) {
            accT[nt] = __builtin_amdgcn_mfma_f32_16x16x32_bf16(A2h[kt], Ch[nt][kt], accT[nt], 0, 0, 0);
            accT[nt] = __builtin_amdgcn_mfma_f32_16x16x32_bf16(A2h[kt], Cl[nt][kt], accT[nt], 0, 0, 0);
            accT[nt] = __builtin_amdgcn_mfma_f32_16x16x32_bf16(A2l[kt], Ch[nt][kt], accT[nt], 0, 0, 0);
        }
    }

    // dump Y to LDS (reuse Ul) then coalesced store
    float* Yl = (float*)&Ul[0][0];       // stride 68
#pragma unroll
    for (int nt = 0; nt < 4; ++nt)
#pragma unroll
        for (int e = 0; e < 4; ++e)
            Yl[(nt * 16 + n15) * 68 + wave * 16 + kg * 4 + e] = accT[nt][e];
    __syncthreads();
    {
        int c = tid >> 2;
        int j0 = (tid & 3) << 4;
        float* yp = yrow + ((size_t)tid << 4);
#pragma unroll
        for (int q = 0; q < 4; ++q)
            *(float4*)(yp + q * 4) = *(const float4*)&Yl[c * 68 + j0 + q * 4];
    }
}

// ---------------- conv(1x1 H->2H) via MFMA bf16 hi/lo + GLU + residual + LayerNorm (unchanged R6) ----------------
__global__ __launch_bounds__(256, 2) void k_conv(float* __restrict__ hbuf, const float* __restrict__ ybuf,
                                                 const short* __restrict__ Ahi, const short* __restrict__ Alo,
                                                 const float* __restrict__ out_b, const float* __restrict__ Dp,
                                                 const float* __restrict__ ln_g, const float* __restrict__ ln_b,
                                                 int layer) {
    __shared__ unsigned gs[64 * 132];
    __shared__ float    us[64 * 133];
    int tid = threadIdx.x;
    int blk = blockIdx.x;                 // B * (L/64)
    int b   = blk >> 6;
    int l0  = (blk & 63) << 6;
    const float* Drow = Dp + layer * HH;

    {
        int w  = tid >> 6;
        int t6 = tid & 63;
        int lq = (t6 & 15) * 4;
        int hb = 32 * w + 8 * (t6 >> 4);
#pragma unroll
        for (int i = 0; i < 8; ++i) {
            int h = hb + i;
            float d = Drow[h];
            size_t base = ((size_t)(b * HH + h)) * LL + l0 + lq;
            float4 yv = *(const float4*)(ybuf + base);
            float4 uv = *(const float4*)(hbuf + base);
            float ys[4] = {yv.x, yv.y, yv.z, yv.w};
            float uu[4] = {uv.x, uv.y, uv.z, uv.w};
#pragma unroll
            for (int j = 0; j < 4; ++j) {
                int l = lq + j;
                float t = fmaf(d, uu[j], ys[j]);
                float g = 0.5f * t * (1.0f + erff(t * 0.70710678118654752f));
                unsigned short gh = f2bf(g);
                unsigned short gl = f2bf(g - bf2f(gh));
                gs[l * 132 + ((((h >> 2) ^ (l & 7)) << 2) | (h & 3))] = ((unsigned)gh << 16) | (unsigned)gl;
                us[l * 133 + h] = uu[j];
            }
        }
    }
    __syncthreads();

    int wave = tid >> 6;
    int lane = tid & 63;
    int n    = lane & 15;
    int kg   = lane >> 4;
    int ll2  = wave * 16 + n;

    short8 Bhi[4], Blo[4];
#pragma unroll
    for (int ks = 0; ks < 4; ++ks) {
        int G0 = 8 * ks + 2 * kg;
        uint4 w0 = *(const uint4*)&gs[ll2 * 132 + (((G0)     ^ (ll2 & 7)) << 2)];
        uint4 w1 = *(const uint4*)&gs[ll2 * 132 + (((G0 + 1) ^ (ll2 & 7)) << 2)];
        unsigned wv[8] = {w0.x, w0.y, w0.z, w0.w, w1.x, w1.y, w1.z, w1.w};
#pragma unroll
        for (int e = 0; e < 8; ++e) {
            Bhi[ks][e] = (short)(wv[e] >> 16);
            Blo[ks][e] = (short)(wv[e] & 0xFFFFu);
        }
    }

    f32x4 acc[16];
#pragma unroll
    for (int ot = 0; ot < 16; ++ot) acc[ot] = (f32x4)(0.0f);

    const short* Abase_hi = Ahi + ((size_t)(layer * 16) * 4 * 64) * 8;
    const short* Abase_lo = Alo + ((size_t)(layer * 16) * 4 * 64) * 8;
#pragma unroll
    for (int ot = 0; ot < 16; ++ot) {
#pragma unroll
        for (int ks = 0; ks < 4; ++ks) {
            size_t aoff = ((size_t)(ot * 4 + ks) * 64 + lane) * 8;
            short8 ah = *(const short8*)(Abase_hi + aoff);
            short8 al = *(const short8*)(Abase_lo + aoff);
            acc[ot] = __builtin_amdgcn_mfma_f32_16x16x32_bf16(ah, Bhi[ks], acc[ot], 0, 0, 0);
            acc[ot] = __builtin_amdgcn_mfma_f32_16x16x32_bf16(ah, Blo[ks], acc[ot], 0, 0, 0);
            acc[ot] = __builtin_amdgcn_mfma_f32_16x16x32_bf16(al, Bhi[ks], acc[ot], 0, 0, 0);
        }
    }

    size_t lpos = (size_t)l0 + ll2;
    const float* obL = out_b + layer * TWOH;
    float s = 0.0f, qq = 0.0f;
#pragma unroll
    for (int ot = 0; ot < 8; ++ot) {
#pragma unroll
        for (int e = 0; e < 4; ++e) {
            int ch = ot * 16 + kg * 4 + e;
            float a = acc[ot][e] + obL[ch];
            float g = acc[ot + 8][e] + obL[ch + 128];
            float sg = 1.0f / (1.0f + expf(-g));
            float z = fmaf(a, sg, us[ll2 * 133 + ch]);
            acc[ot][e] = z;
            s += z; qq += z * z;
        }
    }
    s += __shfl_xor(s, 16); qq += __shfl_xor(qq, 16);
    s += __shfl_xor(s, 32); qq += __shfl_xor(qq, 32);
    float mu  = s * (1.0f / 128.0f);
    float var = qq * (1.0f / 128.0f) - mu * mu;
    float rs  = rsqrtf(var + 1e-5f);
    const float* lgL = ln_g + layer * HH;
    const float* lbL = ln_b + layer * HH;
#pragma unroll
    for (int ot = 0; ot < 8; ++ot) {
#pragma unroll
        for (int e = 0; e < 4; ++e) {
            int ch = ot * 16 + kg * 4 + e;
            hbuf[((size_t)(b * HH + ch)) * LL + lpos] = (acc[ot][e] - mu) * rs * lgL[ch] + lbL[ch];
        }
    }
}

// ---------------- mean pool over L ----------------
__global__ __launch_bounds__(64) void k_pool(const float* __restrict__ hbuf, float* __restrict__ pooled) {
    int row = blockIdx.x;
    int t = threadIdx.x;
    const float* p = hbuf + (size_t)row * LL;
    float s = 0.0f;
    for (int l = t; l < LL; l += 64) s += p[l];
    s += __shfl_xor(s, 32); s += __shfl_xor(s, 16); s += __shfl_xor(s, 8);
    s += __shfl_xor(s, 4);  s += __shfl_xor(s, 2);  s += __shfl_xor(s, 1);
    if (t == 0) pooled[row] = s * (1.0f / LL);
}

// ---------------- decoder ----------------
__global__ __launch_bounds__(256) void k_dec(const float* __restrict__ pooled, const float* __restrict__ dec_w,
                                             const float* __restrict__ dec_b, float* __restrict__ out) {
    int idx = blockIdx.x * 256 + threadIdx.x;
    if (idx >= BB * DOUTN) return;
    int o = idx % DOUTN;
    int b = idx / DOUTN;
    float s = dec_b[o];
    for (int h = 0; h < HH; ++h) s = fmaf(dec_w[o * HH + h], pooled[b * HH + h], s);
    out[idx] = s;
}

extern "C" void kernel_launch(void* const* d_in, const int* in_sizes, int n_in,
                              void* d_out, int out_size, void* d_ws, size_t ws_size,
                              hipStream_t stream) {
    const float* x          = (const float*)d_in[0];
    const float* enc_w      = (const float*)d_in[1];
    const float* enc_b      = (const float*)d_in[2];
    const float* log_dt     = (const float*)d_in[3];
    const float* C          = (const float*)d_in[4];
    const float* log_A_real = (const float*)d_in[5];
    const float* A_imag     = (const float*)d_in[6];
    const float* D          = (const float*)d_in[7];
    const float* out_w      = (const float*)d_in[8];
    const float* out_b      = (const float*)d_in[9];
    const float* ln_g       = (const float*)d_in[10];
    const float* ln_b       = (const float*)d_in[11];
    const float* dec_w      = (const float*)d_in[12];
    const float* dec_b      = (const float*)d_in[13];
    float* out = (float*)d_out;

    float* hbuf   = (float*)d_ws;                                  // B*H*L fp32
    float* ybuf   = hbuf + (size_t)BB * HH * LL;                   // B*H*L fp32
    short* AhiW   = (short*)(ybuf + (size_t)BB * HH * LL);         // conv W frags hi (131072*8 shorts? -> 16384*8)
    short* AloW   = AhiW + (size_t)NLAYERS * 16 * 4 * 64 * 8;
    short* SAhi   = AloW + (size_t)NLAYERS * 16 * 4 * 64 * 8;      // scan mats hi: 128*24*64*8 shorts
    short* SAlo   = SAhi + (size_t)HH * 24 * 64 * 8;
    float* pooled = (float*)(SAlo + (size_t)HH * 24 * 64 * 8);

    hipLaunchKernelGGL(k_pack, dim3(64), dim3(256), 0, stream, out_w, AhiW, AloW);
    hipLaunchKernelGGL(k_enc, dim3(BB * HH * LL / 4 / 256), dim3(256), 0, stream, x, enc_w, enc_b, hbuf);
    for (int layer = 0; layer < NLAYERS; ++layer) {
        hipLaunchKernelGGL(k_mats, dim3(HH), dim3(64), 0, stream,
                           log_dt, C, log_A_real, A_imag, layer, SAhi, SAlo);
        hipLaunchKernelGGL(k_scan, dim3(BB * HH), dim3(256), 0, stream,
                           hbuf, ybuf, log_dt, log_A_real, A_imag, SAhi, SAlo, layer);
        hipLaunchKernelGGL(k_conv, dim3(BB * (LL / 64)), dim3(256), 0, stream,
                           hbuf, ybuf, AhiW, AloW, out_b, D, ln_g, ln_b, layer);
    }
    hipLaunchKernelGGL(k_pool, dim3(BB * HH), dim3(64), 0, stream, hbuf, pooled);
    hipLaunchKernelGGL(k_dec, dim3((BB * DOUTN + 255) / 256), dim3(256), 0, stream, pooled, dec_w, dec_b, out);
}

// Round 8
// 409.588 us; speedup vs baseline: 1.8685x; 1.8685x over previous
//
#include <hip/hip_runtime.h>
#include <math.h>

#define BB 16
#define LL 4096
#define HH 128
#define NN2 32
#define NLAYERS 4
#define DOUTN 100
#define TWOH 256

typedef __attribute__((ext_vector_type(8))) short short8;
typedef __attribute__((ext_vector_type(4))) float f32x4;

__device__ __forceinline__ unsigned short f2bf(float f) {
    unsigned int u = __builtin_bit_cast(unsigned int, f);
    unsigned int r = (u + 0x7FFFu + ((u >> 16) & 1u)) >> 16;
    return (unsigned short)r;
}
__device__ __forceinline__ float bf2f(unsigned short s) {
    unsigned int u = ((unsigned int)s) << 16;
    return __builtin_bit_cast(float, u);
}
__device__ __forceinline__ unsigned packbf(float v) {
    unsigned short hh = f2bf(v);
    unsigned short ll = f2bf(v - bf2f(hh));
    return ((unsigned)hh << 16) | (unsigned)ll;
}

// ---------------- pack out_w (nl,2H,H) into MFMA A-fragment layout, bf16 hi/lo ----------------
__global__ __launch_bounds__(256) void k_pack(const float* __restrict__ out_w,
                                              short* __restrict__ Ahi, short* __restrict__ Alo) {
    int idx = blockIdx.x * 256 + threadIdx.x;          // 4*16*4*64 = 16384
    if (idx >= NLAYERS * 16 * 4 * 64) return;
    int lane = idx & 63;
    int ks   = (idx >> 6) & 3;
    int ot   = (idx >> 8) & 15;
    int layer = idx >> 12;
    int o = ot * 16 + (lane & 15);
    short8 hi, lo;
#pragma unroll
    for (int e = 0; e < 8; ++e) {
        int h = ks * 32 + (lane >> 4) * 8 + e;
        float w = out_w[((size_t)(layer * TWOH + o)) * HH + h];
        unsigned short wh = f2bf(w);
        hi[e] = (short)wh;
        lo[e] = (short)f2bf(w - bf2f(wh));
    }
    *(short8*)(Ahi + (size_t)idx * 8) = hi;
    *(short8*)(Alo + (size_t)idx * 8) = lo;
}

// ---------------- build per-(layer,h) scan matrices as MFMA A-frags (ALL layers, one launch) ----
// Block = one (layer,h). 4 waves: wave w computes modes 8w..8w+7 of F/E and the kernel k,
// then packs 6 of the 24 fragments. Also writes M = lambda^64 per mode (for k_scan prefix).
__global__ __launch_bounds__(256) void k_mats(const float* __restrict__ log_dt, const float* __restrict__ Cc,
                                              const float* __restrict__ log_A_real, const float* __restrict__ A_imag,
                                              short* __restrict__ SAhi, short* __restrict__ SAlo,
                                              float2* __restrict__ Mlam) {
    __shared__ float kker[64];
    __shared__ float kp[4][64];
    __shared__ float Mb[128][66];
    __shared__ float El[64][66];
    int blk = blockIdx.x;                 // layer*128 + h
    int layer = blk >> 7;
    int h = blk & 127;
    int tid = threadIdx.x;
    int wave = tid >> 6, lane = tid & 63;
    float dt = expf(log_dt[layer * HH + h]);
    float kacc = 0.0f;
    float fl = (float)lane;
    float f2_ = (float)(63 - lane);
#pragma unroll 1
    for (int q = 0; q < 8; ++q) {
        int n = wave * 8 + q;
        int pidx = (layer * HH + h) * NN2 + n;
        float Ar  = -expf(log_A_real[pidx]);
        float Ai  = A_imag[pidx];
        float dAr = Ar * dt, dAi = Ai * dt;
        float el  = expf(dAr);
        float lr  = el * cosf(dAi), li = el * sinf(dAi);
        float nr  = lr - 1.0f, ni = li;
        float inv = 1.0f / (Ar * Ar + Ai * Ai);
        float gr  = (nr * Ar + ni * Ai) * inv;
        float gi  = (ni * Ar - nr * Ai) * inv;
        float Cre = Cc[pidx * 2], Cim = Cc[pidx * 2 + 1];
        float c2r = 2.0f * (Cre * gr - Cim * gi);
        float c2i = 2.0f * (Cre * gi + Cim * gr);
        float e1 = expf(dAr * fl), a1 = dAi * fl;
        float p1r = e1 * cosf(a1), p1i = e1 * sinf(a1);
        kacc += c2r * p1r - c2i * p1i;
        float e2 = expf(dAr * f2_), a2 = dAi * f2_;
        Mb[64 + 2 * n][lane]     = e2 * cosf(a2);
        Mb[64 + 2 * n + 1][lane] = e2 * sinf(a2);
        float p3r = lr * p1r - li * p1i;
        float p3i = lr * p1i + li * p1r;
        El[lane][2 * n]     =  c2r * p3r - c2i * p3i;
        El[lane][2 * n + 1] = -(c2r * p3i + c2i * p3r);
    }
    kp[wave][lane] = kacc;
    __syncthreads();
    if (wave == 0) kker[lane] = kp[0][lane] + kp[1][lane] + kp[2][lane] + kp[3][lane];
    __syncthreads();
#pragma unroll
    for (int jj = 0; jj < 16; ++jj) {
        int j = wave * 16 + jj;
        Mb[j][lane] = (j >= lane) ? kker[j - lane] : 0.0f;
    }
    __syncthreads();
    // M = lambda^64 per mode (threads 0..31)
    if (tid < 32) {
        int n = tid;
        int pidx = (layer * HH + h) * NN2 + n;
        float Ar = -expf(log_A_real[pidx]);
        float Ai = A_imag[pidx];
        float dAr = Ar * dt, dAi = Ai * dt;
        float e64 = expf(dAr * 64.0f), a64 = dAi * 64.0f;
        Mlam[pidx] = make_float2(e64 * cosf(a64), e64 * sinf(a64));
    }
    // pack 24 frags (6 per wave): f 0..15 = [T;F] (mt*2+kt), 16..23 = E
    int r = lane & 15, kgq = lane >> 4;
    short* baseH = SAhi + (size_t)(layer * HH + h) * 24 * 64 * 8;
    short* baseL = SAlo + (size_t)(layer * HH + h) * 24 * 64 * 8;
#pragma unroll 1
    for (int ff = 0; ff < 6; ++ff) {
        int f = wave * 6 + ff;
        int loc = (f < 16) ? f : (f - 16);
        int mt = loc >> 1, kt = loc & 1;
        int rowb = mt * 16 + r;
        int kcol = kt * 32 + kgq * 8;
        short8 hi8, lo8;
#pragma unroll
        for (int e = 0; e < 8; ++e) {
            float v = (f < 16) ? Mb[rowb][kcol + e] : El[rowb][kcol + e];
            unsigned short hh = f2bf(v);
            hi8[e] = (short)hh;
            lo8[e] = (short)f2bf(v - bf2f(hh));
        }
        *(short8*)(baseH + ((size_t)f * 64 + lane) * 8) = hi8;
        *(short8*)(baseL + ((size_t)f * 64 + lane) * 8) = lo8;
    }
}

// ---------------- encoder ----------------
__global__ __launch_bounds__(256) void k_enc(const float* __restrict__ x, const float* __restrict__ enc_w,
                                             const float* __restrict__ enc_b, float* __restrict__ hbuf) {
    int idx = blockIdx.x * 256 + threadIdx.x;
    int l4 = idx & (LL / 4 - 1);
    int h  = (idx / (LL / 4)) & (HH - 1);
    int b  = idx / (LL / 4 * HH);
    float4 xv = ((const float4*)(x + (size_t)b * LL))[l4];
    float w = enc_w[h], bb = enc_b[h];
    float4 o;
    o.x = fmaf(xv.x, w, bb);
    o.y = fmaf(xv.y, w, bb);
    o.z = fmaf(xv.z, w, bb);
    o.w = fmaf(xv.w, w, bb);
    ((float4*)(hbuf + ((size_t)b * HH + h) * LL))[l4] = o;
}

// ---------------- SSM scan via MFMA v2 ----------------
// Y = T*U + E*S_in, S_fin = F*U. Prefix parallelized over all 4 waves (8 modes each),
// M precomputed. LDS 35KB: Ul (packed u -> packed S_in), Sf (S_fin -> Y). 4 barriers.
__global__ __launch_bounds__(256, 4) void k_scan(const float* __restrict__ u_, float* __restrict__ y_,
                                                 const float2* __restrict__ Mlam,
                                                 const short* __restrict__ SAhi, const short* __restrict__ SAlo,
                                                 int layer) {
    __shared__ unsigned Ul[64][68];   // packed bf16 hi|lo of u [chunk][step]; later packed S_in [chunk][comp]
    __shared__ float Sf[64][68];      // S_fin [comp][chunk]; later Y [chunk][step]
    int row = blockIdx.x;             // b*H + h
    int h = row & (HH - 1);
    int tid = threadIdx.x;
    const float* urow = u_ + (size_t)row * LL;
    float* yrow = y_ + (size_t)row * LL;
    int wave = tid >> 6, lane = tid & 63;
    int n15 = lane & 15, kg = lane >> 4;

    // A-frag loads
    const short* bH = SAhi + (size_t)(layer * HH + h) * 24 * 64 * 8;
    const short* bL = SAlo + (size_t)(layer * HH + h) * 24 * 64 * 8;
    short8 A1h0[2], A1l0[2], A1h1[2], A1l1[2], A2h[2], A2l[2];
#pragma unroll
    for (int kt = 0; kt < 2; ++kt) {
        int f0 = wave * 2 + kt;          // T rows (mt = wave)
        int f1 = (wave + 4) * 2 + kt;    // F rows (mt = wave+4)
        int fe = 16 + wave * 2 + kt;     // E rows (mt = wave)
        A1h0[kt] = *(const short8*)(bH + ((size_t)f0 * 64 + lane) * 8);
        A1l0[kt] = *(const short8*)(bL + ((size_t)f0 * 64 + lane) * 8);
        A1h1[kt] = *(const short8*)(bH + ((size_t)f1 * 64 + lane) * 8);
        A1l1[kt] = *(const short8*)(bL + ((size_t)f1 * 64 + lane) * 8);
        A2h[kt]  = *(const short8*)(bH + ((size_t)fe * 64 + lane) * 8);
        A2l[kt]  = *(const short8*)(bL + ((size_t)fe * 64 + lane) * 8);
    }
    // M for this wave's 8 modes
    float mr0[8], mi0[8];
#pragma unroll
    for (int m = 0; m < 8; ++m) {
        float2 mv = Mlam[((size_t)layer * HH + h) * NN2 + wave * 8 + m];
        mr0[m] = mv.x; mi0[m] = mv.y;
    }

    // stage u -> LDS packed bf16 hi/lo
    {
        int c  = tid >> 2;
        int i0 = (tid & 3) << 4;
        const float* up = urow + ((size_t)tid << 4);
        float vv[16];
        *(float4*)&vv[0]  = *(const float4*)(up);
        *(float4*)&vv[4]  = *(const float4*)(up + 4);
        *(float4*)&vv[8]  = *(const float4*)(up + 8);
        *(float4*)&vv[12] = *(const float4*)(up + 12);
#pragma unroll
        for (int q = 0; q < 4; ++q) {
            uint4 w;
            w.x = packbf(vv[q * 4 + 0]);
            w.y = packbf(vv[q * 4 + 1]);
            w.z = packbf(vv[q * 4 + 2]);
            w.w = packbf(vv[q * 4 + 3]);
            *(uint4*)&Ul[c][i0 + q * 4] = w;
        }
    }
    __syncthreads();

    // U B-frags
    short8 Bh[4][2], Bl[4][2];
#pragma unroll
    for (int nt = 0; nt < 4; ++nt) {
        int c = nt * 16 + n15;
#pragma unroll
        for (int kt = 0; kt < 2; ++kt) {
            int i0 = kt * 32 + kg * 8;
            uint4 w0 = *(const uint4*)&Ul[c][i0];
            uint4 w1 = *(const uint4*)&Ul[c][i0 + 4];
            unsigned wv[8] = {w0.x, w0.y, w0.z, w0.w, w1.x, w1.y, w1.z, w1.w};
#pragma unroll
            for (int e = 0; e < 8; ++e) {
                Bh[nt][kt][e] = (short)(wv[e] >> 16);
                Bl[nt][kt][e] = (short)(wv[e] & 0xFFFFu);
            }
        }
    }

    // GEMM1: [T;F] x U  (3-pass hi/lo)
    f32x4 accT[4], accF[4];
#pragma unroll
    for (int nt = 0; nt < 4; ++nt) { accT[nt] = (f32x4)(0.0f); accF[nt] = (f32x4)(0.0f); }
#pragma unroll
    for (int nt = 0; nt < 4; ++nt) {
#pragma unroll
        for (int kt = 0; kt < 2; ++kt) {
            accT[nt] = __builtin_amdgcn_mfma_f32_16x16x32_bf16(A1h0[kt], Bh[nt][kt], accT[nt], 0, 0, 0);
            accT[nt] = __builtin_amdgcn_mfma_f32_16x16x32_bf16(A1h0[kt], Bl[nt][kt], accT[nt], 0, 0, 0);
            accT[nt] = __builtin_amdgcn_mfma_f32_16x16x32_bf16(A1l0[kt], Bh[nt][kt], accT[nt], 0, 0, 0);
            accF[nt] = __builtin_amdgcn_mfma_f32_16x16x32_bf16(A1h1[kt], Bh[nt][kt], accF[nt], 0, 0, 0);
            accF[nt] = __builtin_amdgcn_mfma_f32_16x16x32_bf16(A1h1[kt], Bl[nt][kt], accF[nt], 0, 0, 0);
            accF[nt] = __builtin_amdgcn_mfma_f32_16x16x32_bf16(A1l1[kt], Bh[nt][kt], accF[nt], 0, 0, 0);
        }
    }

    // dump S_fin [comp][chunk]
#pragma unroll
    for (int nt = 0; nt < 4; ++nt)
#pragma unroll
        for (int e = 0; e < 4; ++e)
            Sf[wave * 16 + kg * 4 + e][nt * 16 + n15] = accF[nt][e];
    __syncthreads();

    // prefix: ALL 4 waves, 8 modes each (comps [16w,16w+16)); write packed S_in into Ul
    {
        float srr[8], sii[8], mr[8], mi[8];
#pragma unroll
        for (int m = 0; m < 8; ++m) {
            mr[m] = mr0[m]; mi[m] = mi0[m];
            srr[m] = Sf[wave * 16 + 2 * m][lane];
            sii[m] = Sf[wave * 16 + 2 * m + 1][lane];
        }
#pragma unroll
        for (int k = 1; k < 64; k <<= 1) {
#pragma unroll
            for (int m = 0; m < 8; ++m) {
                float vr = __shfl_up(srr[m], k);
                float vi = __shfl_up(sii[m], k);
                vr = (lane >= k) ? vr : 0.0f;
                vi = (lane >= k) ? vi : 0.0f;
                srr[m] = fmaf(mr[m], vr, fmaf(-mi[m], vi, srr[m]));
                sii[m] = fmaf(mr[m], vi, fmaf(mi[m], vr, sii[m]));
            }
#pragma unroll
            for (int m = 0; m < 8; ++m) {
                float t = fmaf(mr[m], mr[m], -(mi[m] * mi[m]));
                mi[m] = 2.0f * mr[m] * mi[m];
                mr[m] = t;
            }
        }
#pragma unroll
        for (int m = 0; m < 8; ++m) {
            float vr = __shfl_up(srr[m], 1);
            float vi = __shfl_up(sii[m], 1);
            vr = (lane >= 1) ? vr : 0.0f;
            vi = (lane >= 1) ? vi : 0.0f;
            Ul[lane][wave * 16 + 2 * m]     = packbf(vr);
            Ul[lane][wave * 16 + 2 * m + 1] = packbf(vi);
        }
    }
    __syncthreads();

    // S_in B-frags (packed) + GEMM2: += E x S_in
#pragma unroll
    for (int nt = 0; nt < 4; ++nt) {
        int c = nt * 16 + n15;
#pragma unroll
        for (int kt = 0; kt < 2; ++kt) {
            int k0 = kt * 32 + kg * 8;
            uint4 w0 = *(const uint4*)&Ul[c][k0];
            uint4 w1 = *(const uint4*)&Ul[c][k0 + 4];
            unsigned wv[8] = {w0.x, w0.y, w0.z, w0.w, w1.x, w1.y, w1.z, w1.w};
            short8 ch, cl;
#pragma unroll
            for (int e = 0; e < 8; ++e) {
                ch[e] = (short)(wv[e] >> 16);
                cl[e] = (short)(wv[e] & 0xFFFFu);
            }
            accT[nt] = __builtin_amdgcn_mfma_f32_16x16x32_bf16(A2h[kt], ch, accT[nt], 0, 0, 0);
            accT[nt] = __builtin_amdgcn_mfma_f32_16x16x32_bf16(A2h[kt], cl, accT[nt], 0, 0, 0);
            accT[nt] = __builtin_amdgcn_mfma_f32_16x16x32_bf16(A2l[kt], ch, accT[nt], 0, 0, 0);
        }
    }

    // dump Y into Sf region, then coalesced store
    float* Yl = &Sf[0][0];
#pragma unroll
    for (int nt = 0; nt < 4; ++nt)
#pragma unroll
        for (int e = 0; e < 4; ++e)
            Yl[(nt * 16 + n15) * 68 + wave * 16 + kg * 4 + e] = accT[nt][e];
    __syncthreads();
    {
        int c = tid >> 2;
        int j0 = (tid & 3) << 4;
        float* yp = yrow + ((size_t)tid << 4);
#pragma unroll
        for (int q = 0; q < 4; ++q)
            *(float4*)(yp + q * 4) = *(const float4*)&Yl[c * 68 + j0 + q * 4];
    }
}

// ---------------- conv(1x1 H->2H) via MFMA bf16 hi/lo + GLU + residual + LayerNorm (R6) ----------------
__global__ __launch_bounds__(256, 2) void k_conv(float* __restrict__ hbuf, const float* __restrict__ ybuf,
                                                 const short* __restrict__ Ahi, const short* __restrict__ Alo,
                                                 const float* __restrict__ out_b, const float* __restrict__ Dp,
                                                 const float* __restrict__ ln_g, const float* __restrict__ ln_b,
                                                 int layer) {
    __shared__ unsigned gs[64 * 132];
    __shared__ float    us[64 * 133];
    int tid = threadIdx.x;
    int blk = blockIdx.x;                 // B * (L/64)
    int b   = blk >> 6;
    int l0  = (blk & 63) << 6;
    const float* Drow = Dp + layer * HH;

    {
        int w  = tid >> 6;
        int t6 = tid & 63;
        int lq = (t6 & 15) * 4;
        int hb = 32 * w + 8 * (t6 >> 4);
#pragma unroll
        for (int i = 0; i < 8; ++i) {
            int h = hb + i;
            float d = Drow[h];
            size_t base = ((size_t)(b * HH + h)) * LL + l0 + lq;
            float4 yv = *(const float4*)(ybuf + base);
            float4 uv = *(const float4*)(hbuf + base);
            float ys[4] = {yv.x, yv.y, yv.z, yv.w};
            float uu[4] = {uv.x, uv.y, uv.z, uv.w};
#pragma unroll
            for (int j = 0; j < 4; ++j) {
                int l = lq + j;
                float t = fmaf(d, uu[j], ys[j]);
                float g = 0.5f * t * (1.0f + erff(t * 0.70710678118654752f));
                unsigned short gh = f2bf(g);
                unsigned short gl = f2bf(g - bf2f(gh));
                gs[l * 132 + ((((h >> 2) ^ (l & 7)) << 2) | (h & 3))] = ((unsigned)gh << 16) | (unsigned)gl;
                us[l * 133 + h] = uu[j];
            }
        }
    }
    __syncthreads();

    int wave = tid >> 6;
    int lane = tid & 63;
    int n    = lane & 15;
    int kg   = lane >> 4;
    int ll2  = wave * 16 + n;

    short8 Bhi[4], Blo[4];
#pragma unroll
    for (int ks = 0; ks < 4; ++ks) {
        int G0 = 8 * ks + 2 * kg;
        uint4 w0 = *(const uint4*)&gs[ll2 * 132 + (((G0)     ^ (ll2 & 7)) << 2)];
        uint4 w1 = *(const uint4*)&gs[ll2 * 132 + (((G0 + 1) ^ (ll2 & 7)) << 2)];
        unsigned wv[8] = {w0.x, w0.y, w0.z, w0.w, w1.x, w1.y, w1.z, w1.w};
#pragma unroll
        for (int e = 0; e < 8; ++e) {
            Bhi[ks][e] = (short)(wv[e] >> 16);
            Blo[ks][e] = (short)(wv[e] & 0xFFFFu);
        }
    }

    f32x4 acc[16];
#pragma unroll
    for (int ot = 0; ot < 16; ++ot) acc[ot] = (f32x4)(0.0f);

    const short* Abase_hi = Ahi + ((size_t)(layer * 16) * 4 * 64) * 8;
    const short* Abase_lo = Alo + ((size_t)(layer * 16) * 4 * 64) * 8;
#pragma unroll
    for (int ot = 0; ot < 16; ++ot) {
#pragma unroll
        for (int ks = 0; ks < 4; ++ks) {
            size_t aoff = ((size_t)(ot * 4 + ks) * 64 + lane) * 8;
            short8 ah = *(const short8*)(Abase_hi + aoff);
            short8 al = *(const short8*)(Abase_lo + aoff);
            acc[ot] = __builtin_amdgcn_mfma_f32_16x16x32_bf16(ah, Bhi[ks], acc[ot], 0, 0, 0);
            acc[ot] = __builtin_amdgcn_mfma_f32_16x16x32_bf16(ah, Blo[ks], acc[ot], 0, 0, 0);
            acc[ot] = __builtin_amdgcn_mfma_f32_16x16x32_bf16(al, Bhi[ks], acc[ot], 0, 0, 0);
        }
    }

    size_t lpos = (size_t)l0 + ll2;
    const float* obL = out_b + layer * TWOH;
    float s = 0.0f, qq = 0.0f;
#pragma unroll
    for (int ot = 0; ot < 8; ++ot) {
#pragma unroll
        for (int e = 0; e < 4; ++e) {
            int ch = ot * 16 + kg * 4 + e;
            float a = acc[ot][e] + obL[ch];
            float g = acc[ot + 8][e] + obL[ch + 128];
            float sg = 1.0f / (1.0f + expf(-g));
            float z = fmaf(a, sg, us[ll2 * 133 + ch]);
            acc[ot][e] = z;
            s += z; qq += z * z;
        }
    }
    s += __shfl_xor(s, 16); qq += __shfl_xor(qq, 16);
    s += __shfl_xor(s, 32); qq += __shfl_xor(qq, 32);
    float mu  = s * (1.0f / 128.0f);
    float var = qq * (1.0f / 128.0f) - mu * mu;
    float rs  = rsqrtf(var + 1e-5f);
    const float* lgL = ln_g + layer * HH;
    const float* lbL = ln_b + layer * HH;
#pragma unroll
    for (int ot = 0; ot < 8; ++ot) {
#pragma unroll
        for (int e = 0; e < 4; ++e) {
            int ch = ot * 16 + kg * 4 + e;
            hbuf[((size_t)(b * HH + ch)) * LL + lpos] = (acc[ot][e] - mu) * rs * lgL[ch] + lbL[ch];
        }
    }
}

// ---------------- mean pool over L ----------------
__global__ __launch_bounds__(64) void k_pool(const float* __restrict__ hbuf, float* __restrict__ pooled) {
    int row = blockIdx.x;
    int t = threadIdx.x;
    const float* p = hbuf + (size_t)row * LL;
    float s = 0.0f;
    for (int l = t; l < LL; l += 64) s += p[l];
    s += __shfl_xor(s, 32); s += __shfl_xor(s, 16); s += __shfl_xor(s, 8);
    s += __shfl_xor(s, 4);  s += __shfl_xor(s, 2);  s += __shfl_xor(s, 1);
    if (t == 0) pooled[row] = s * (1.0f / LL);
}

// ---------------- decoder ----------------
__global__ __launch_bounds__(256) void k_dec(const float* __restrict__ pooled, const float* __restrict__ dec_w,
                                             const float* __restrict__ dec_b, float* __restrict__ out) {
    int idx = blockIdx.x * 256 + threadIdx.x;
    if (idx >= BB * DOUTN) return;
    int o = idx % DOUTN;
    int b = idx / DOUTN;
    float s = dec_b[o];
    for (int h = 0; h < HH; ++h) s = fmaf(dec_w[o * HH + h], pooled[b * HH + h], s);
    out[idx] = s;
}

extern "C" void kernel_launch(void* const* d_in, const int* in_sizes, int n_in,
                              void* d_out, int out_size, void* d_ws, size_t ws_size,
                              hipStream_t stream) {
    const float* x          = (const float*)d_in[0];
    const float* enc_w      = (const float*)d_in[1];
    const float* enc_b      = (const float*)d_in[2];
    const float* log_dt     = (const float*)d_in[3];
    const float* C          = (const float*)d_in[4];
    const float* log_A_real = (const float*)d_in[5];
    const float* A_imag     = (const float*)d_in[6];
    const float* D          = (const float*)d_in[7];
    const float* out_w      = (const float*)d_in[8];
    const float* out_b      = (const float*)d_in[9];
    const float* ln_g       = (const float*)d_in[10];
    const float* ln_b       = (const float*)d_in[11];
    const float* dec_w      = (const float*)d_in[12];
    const float* dec_b      = (const float*)d_in[13];
    float* out = (float*)d_out;

    float* hbuf   = (float*)d_ws;                                  // B*H*L fp32 (32 MB)
    float* ybuf   = hbuf + (size_t)BB * HH * LL;                   // B*H*L fp32 (32 MB)
    short* AhiW   = (short*)(ybuf + (size_t)BB * HH * LL);         // 16384*8 shorts (256 KB)
    short* AloW   = AhiW + (size_t)NLAYERS * 16 * 4 * 64 * 8;
    short* SAhi   = AloW + (size_t)NLAYERS * 16 * 4 * 64 * 8;      // 4*128*24*64*8 shorts (12.6 MB)
    short* SAlo   = SAhi + (size_t)NLAYERS * HH * 24 * 64 * 8;
    float2* Mlam  = (float2*)(SAlo + (size_t)NLAYERS * HH * 24 * 64 * 8);  // 16384 float2
    float* pooled = (float*)(Mlam + (size_t)NLAYERS * HH * NN2);

    hipLaunchKernelGGL(k_pack, dim3(64), dim3(256), 0, stream, out_w, AhiW, AloW);
    hipLaunchKernelGGL(k_mats, dim3(NLAYERS * HH), dim3(256), 0, stream,
                       log_dt, C, log_A_real, A_imag, SAhi, SAlo, Mlam);
    hipLaunchKernelGGL(k_enc, dim3(BB * HH * LL / 4 / 256), dim3(256), 0, stream, x, enc_w, enc_b, hbuf);
    for (int layer = 0; layer < NLAYERS; ++layer) {
        hipLaunchKernelGGL(k_scan, dim3(BB * HH), dim3(256), 0, stream,
                           hbuf, ybuf, Mlam, SAhi, SAlo, layer);
        hipLaunchKernelGGL(k_conv, dim3(BB * (LL / 64)), dim3(256), 0, stream,
                           hbuf, ybuf, AhiW, AloW, out_b, D, ln_g, ln_b, layer);
    }
    hipLaunchKernelGGL(k_pool, dim3(BB * HH), dim3(64), 0, stream, hbuf, pooled);
    hipLaunchKernelGGL(k_dec, dim3((BB * DOUTN + 255) / 256), dim3(256), 0, stream, pooled, dec_w, dec_b, out);
}